// Round 1
// baseline (5410.442 us; speedup 1.0000x reference)
//
#include <hip/hip_runtime.h>
#include <math.h>

// Problem constants
#define NFFT 2048
#define FL   1025          // rfft length
#define CH   512           // d_model
#define NHD  8
#define BB   16

// ---------------------------------------------------------------------------
// In-LDS radix-2 DIT FFT, 2048 points, 256 threads. Data must be loaded in
// bit-reversed order. dir=-1 forward, +1 inverse (caller applies 1/N).
static __device__ __forceinline__ void fft2048_stages(float* re, float* im, int tid, int dir) {
  for (int len = 2; len <= 2048; len <<= 1) {
    int half = len >> 1;
    __syncthreads();
    for (int t = tid; t < 1024; t += 256) {
      int j  = t & (half - 1);
      int i0 = ((t & ~(half - 1)) << 1) | j;
      int i1 = i0 + half;
      float ang = (2.0f * (float)j) / (float)len;   // angle/pi
      float wr = cospif(ang);
      float s  = sinpif(ang);
      float wi = (dir > 0) ? s : -s;
      float vr = re[i1], vi = im[i1];
      float tr = vr * wr - vi * wi;
      float ti = vr * wi + vi * wr;
      float ur = re[i0], ui = im[i0];
      re[i0] = ur + tr; im[i0] = ui + ti;
      re[i1] = ur - tr; im[i1] = ui - ti;
    }
  }
  __syncthreads();
}

// rfft over L for one (b,c) sequence. x: (B, 2048, 512). Output planes:
// QF[b][k][f], k=c -> Re, k=512+c -> Im, row length 1025.
__global__ __launch_bounds__(256) void rfft_kernel(const float* __restrict__ x,
                                                   float* __restrict__ QF) {
  __shared__ float re[2048];
  __shared__ float im[2048];
  int c = blockIdx.x;   // 0..511
  int b = blockIdx.y;   // 0..15
  int tid = threadIdx.x;
  const float* xp = x + (long long)b * 2048 * 512 + c;
  for (int l = tid; l < 2048; l += 256) {
    int r = __brev((unsigned)l) >> 21;   // 11-bit reverse
    re[r] = xp[(long long)l * 512];
    im[r] = 0.f;
  }
  fft2048_stages(re, im, tid, -1);
  float* outRe = QF + ((long long)b * 1024 + c) * FL;
  float* outIm = QF + ((long long)b * 1024 + 512 + c) * FL;
  for (int f = tid; f < FL; f += 256) { outRe[f] = re[f]; outIm[f] = im[f]; }
}

// irfft (n=2048) for one (b,d) pair. y: (B, 1025, 1024) with complex pairs
// interleaved (re at 2d, im at 2d+1). out: (B, 2048, 512).
__global__ __launch_bounds__(256) void irfft_kernel(const float* __restrict__ y,
                                                    float* __restrict__ out) {
  __shared__ float nre[FL];
  __shared__ float nim[FL];
  __shared__ float re[2048];
  __shared__ float im[2048];
  int d = blockIdx.x;   // 0..511
  int b = blockIdx.y;   // 0..15
  int tid = threadIdx.x;
  const float* yp = y + (long long)b * FL * 1024 + 2 * d;
  for (int f = tid; f < FL; f += 256) {
    nre[f] = yp[(long long)f * 1024];
    nim[f] = yp[(long long)f * 1024 + 1];
  }
  __syncthreads();
  // Hermitian extension into bit-reversed positions. Taking Re() of the
  // complex iFFT automatically matches c2r semantics (imag of DC/Nyquist
  // cannot affect the real output).
  for (int i = tid; i < 2048; i += 256) {
    int j = __brev((unsigned)i) >> 21;
    float r, mi;
    if (j <= 1024) { r = nre[j];        mi =  nim[j]; }
    else           { r = nre[2048 - j]; mi = -nim[2048 - j]; }
    re[i] = r; im[i] = mi;
  }
  fft2048_stages(re, im, tid, +1);
  float* op = out + (long long)b * 2048 * 512 + d;
  const float sc = 1.0f / 2048.0f;
  for (int l = tid; l < 2048; l += 256) op[(long long)l * 512] = re[l] * sc;
}

// ---------------------------------------------------------------------------
// Generic strided fp32 GEMM: C[m,n] = sum_k A[m*sAm + k*sAk] * B[n*sBn + k*sBk]
// (+bias[n]) (+uscale*m*vvec[n]).  Batched over blockIdx.z: b=z/HB, h=z%HB.
// Tile 64x64, Ktile 16, 256 threads, 4x4 per thread.
__global__ __launch_bounds__(256) void gemm_kernel(
    const float* __restrict__ A, const float* __restrict__ B, float* __restrict__ C,
    int M, int N, int K, int HB,
    long long sAm, long long sAk, long long sAb, long long sAh,
    long long sBn, long long sBk, long long sBb, long long sBh,
    long long sCm, long long sCb, long long sCh,
    const float* __restrict__ bias, const float* __restrict__ vvec, float uscale) {
  __shared__ float As[16][65];
  __shared__ float Bs[16][65];
  int tid = threadIdx.x;
  int tx = tid & 15, ty = tid >> 4;
  int m0 = blockIdx.x * 64, n0 = blockIdx.y * 64;
  int z = blockIdx.z;
  int bb = z / HB, hh = z - bb * HB;
  const float* Ab = A + (long long)bb * sAb + (long long)hh * sAh;
  const float* Bb = B + (long long)bb * sBb + (long long)hh * sBh;
  float* Cb = C + (long long)bb * sCb + (long long)hh * sCh;

  float acc[4][4];
#pragma unroll
  for (int i = 0; i < 4; i++)
#pragma unroll
    for (int j = 0; j < 4; j++) acc[i][j] = 0.f;

  for (int k0 = 0; k0 < K; k0 += 16) {
    if (sAk == 1) {
#pragma unroll
      for (int e = tid; e < 1024; e += 256) {
        int kloc = e & 15, mloc = e >> 4;
        int m = m0 + mloc, k = k0 + kloc;
        As[kloc][mloc] = (m < M && k < K) ? Ab[(long long)m * sAm + k] : 0.f;
      }
    } else {
#pragma unroll
      for (int e = tid; e < 1024; e += 256) {
        int mloc = e & 63, kloc = e >> 6;
        int m = m0 + mloc, k = k0 + kloc;
        As[kloc][mloc] = (m < M && k < K) ? Ab[(long long)m * sAm + (long long)k * sAk] : 0.f;
      }
    }
    if (sBk == 1) {
#pragma unroll
      for (int e = tid; e < 1024; e += 256) {
        int kloc = e & 15, nloc = e >> 4;
        int n = n0 + nloc, k = k0 + kloc;
        Bs[kloc][nloc] = (n < N && k < K) ? Bb[(long long)n * sBn + k] : 0.f;
      }
    } else {
#pragma unroll
      for (int e = tid; e < 1024; e += 256) {
        int nloc = e & 63, kloc = e >> 6;
        int n = n0 + nloc, k = k0 + kloc;
        Bs[kloc][nloc] = (n < N && k < K) ? Bb[(long long)n * sBn + (long long)k * sBk] : 0.f;
      }
    }
    __syncthreads();
#pragma unroll
    for (int kk = 0; kk < 16; kk++) {
      float av[4], bv[4];
#pragma unroll
      for (int i = 0; i < 4; i++) av[i] = As[kk][ty + 16 * i];
#pragma unroll
      for (int j = 0; j < 4; j++) bv[j] = Bs[kk][tx + 16 * j];
#pragma unroll
      for (int i = 0; i < 4; i++)
#pragma unroll
        for (int j = 0; j < 4; j++) acc[i][j] += av[i] * bv[j];
    }
    __syncthreads();
  }

#pragma unroll
  for (int i = 0; i < 4; i++) {
#pragma unroll
    for (int j = 0; j < 4; j++) {
      int m = m0 + ty + 16 * i, n = n0 + tx + 16 * j;
      if (m < M && n < N) {
        float val = acc[i][j];
        if (bias) val += bias[n];
        if (vvec) val += uscale * (float)m * vvec[n];
        Cb[(long long)m * sCm + n] = val;
      }
    }
  }
}

// ---------------------------------------------------------------------------
// In-place row softmax over 1025 elements, with scale 1/8 applied first.
__global__ __launch_bounds__(256) void softmax_kernel(float* __restrict__ attn) {
  long long row = blockIdx.x;
  float* p = attn + row * FL;
  int tid = threadIdx.x;
  float x[5];
  float mx = -INFINITY;
#pragma unroll
  for (int k = 0; k < 5; k++) {
    int i = tid + 256 * k;
    x[k] = (i < FL) ? p[i] * 0.125f : -INFINITY;
    mx = fmaxf(mx, x[k]);
  }
  for (int o = 32; o; o >>= 1) mx = fmaxf(mx, __shfl_xor(mx, o, 64));
  __shared__ float sm[4];
  __shared__ float ssum[4];
  int wid = tid >> 6;
  if ((tid & 63) == 0) sm[wid] = mx;
  __syncthreads();
  mx = fmaxf(fmaxf(sm[0], sm[1]), fmaxf(sm[2], sm[3]));
  float sum = 0.f;
#pragma unroll
  for (int k = 0; k < 5; k++) {
    int i = tid + 256 * k;
    x[k] = (i < FL) ? expf(x[k] - mx) : 0.f;
    sum += x[k];
  }
  for (int o = 32; o; o >>= 1) sum += __shfl_xor(sum, o, 64);
  if ((tid & 63) == 0) ssum[wid] = sum;
  __syncthreads();
  sum = ssum[0] + ssum[1] + ssum[2] + ssum[3];
  float rinv = 1.0f / sum;
#pragma unroll
  for (int k = 0; k < 5; k++) {
    int i = tid + 256 * k;
    if (i < FL) p[i] = x[k] * rinv;
  }
}

// ---------------------------------------------------------------------------
// Repack W (O=512, C=512, 3) -> W2 (K=1024, O=512): k<512 uses j=0 (Re),
// k>=512 uses j=1 (Im). blockIdx.y selects q/k/v.
__global__ __launch_bounds__(256) void repack_kernel(const float* __restrict__ Wq,
                                                     const float* __restrict__ Wk,
                                                     const float* __restrict__ Wv,
                                                     float* __restrict__ W2) {
  int idx = blockIdx.x * 256 + threadIdx.x;   // 0 .. 524287
  const float* W = (blockIdx.y == 0) ? Wq : (blockIdx.y == 1) ? Wk : Wv;
  float* W2o = W2 + (long long)blockIdx.y * 524288;
  int k = idx >> 9, o = idx & 511;
  int c = k & 511, j = k >> 9;
  W2o[idx] = W[(long long)o * 1536 + c * 3 + j];
}

// wf[o] = sum_c W[o,c,2]  (the frequency-feature column sums)
__global__ __launch_bounds__(256) void wf_kernel(const float* __restrict__ Wq,
                                                 const float* __restrict__ Wk,
                                                 const float* __restrict__ Wv,
                                                 float* __restrict__ wf) {
  int o = blockIdx.x * 256 + threadIdx.x;   // 0..511 (grid.x=2)
  if (o >= 512) return;
  const float* W = (blockIdx.y == 0) ? Wq : (blockIdx.y == 1) ? Wk : Wv;
  float s = 0.f;
  for (int c = 0; c < 512; c++) s += W[(long long)o * 1536 + c * 3 + 2];
  wf[blockIdx.y * 512 + o] = s;
}

// ---------------------------------------------------------------------------
extern "C" void kernel_launch(void* const* d_in, const int* in_sizes, int n_in,
                              void* d_out, int out_size, void* d_ws, size_t ws_size,
                              hipStream_t stream) {
  (void)in_sizes; (void)n_in; (void)out_size; (void)ws_size;
  const float* q  = (const float*)d_in[0];
  const float* k  = (const float*)d_in[1];
  const float* v  = (const float*)d_in[2];
  const float* Wq = (const float*)d_in[3];
  const float* bq = (const float*)d_in[4];
  const float* Wk = (const float*)d_in[5];
  const float* bk = (const float*)d_in[6];
  const float* Wv = (const float*)d_in[7];
  const float* bv = (const float*)d_in[8];
  const float* Wo = (const float*)d_in[9];
  const float* bo = (const float*)d_in[10];

  float* outp = (float*)d_out;                          // (16, 2048, 512)
  float* attn = outp + (long long)16 * 2048 * 512;      // (16, 8, 1025, 1025)

  float* ws  = (float*)d_ws;
  float* QF  = ws;                       // 16*1024*1025 = 16,793,600 (reused as y)
  float* qh  = QF + 16793600;            // 16*1025*512  =  8,396,800
  float* kh  = qh + 8396800;
  float* vh  = kh + 8396800;
  float* ctx = vh + 8396800;
  float* W2  = ctx + 8396800;            // 3 * 1024*512
  float* wf  = W2 + 3 * 524288;          // 3 * 512
  float* yb  = QF;                       // out-proj result aliases QF

  repack_kernel<<<dim3(2048, 3, 1), 256, 0, stream>>>(Wq, Wk, Wv, W2);
  wf_kernel<<<dim3(2, 3, 1), 256, 0, stream>>>(Wq, Wk, Wv, wf);

  const float uscale = 1.0f / 2048.0f;   // rfftfreq step
  const float* xs[3] = {q, k, v};
  const float* bs[3] = {bq, bk, bv};
  float* hs[3] = {qh, kh, vh};
  for (int t = 0; t < 3; t++) {
    rfft_kernel<<<dim3(512, 16, 1), 256, 0, stream>>>(xs[t], QF);
    // per-b GEMM: (F=1025 x O=512 x K=1024), A = FFT planes (K-major rows)
    gemm_kernel<<<dim3(17, 8, 16), 256, 0, stream>>>(
        QF, W2 + (long long)t * 524288, hs[t],
        1025, 512, 1024, 1,
        /*sAm*/ 1LL, /*sAk*/ 1025LL, /*sAb*/ 1049600LL, /*sAh*/ 0LL,
        /*sBn*/ 1LL, /*sBk*/ 512LL, 0LL, 0LL,
        /*sCm*/ 512LL, /*sCb*/ 524800LL, 0LL,
        bs[t], wf + t * 512, uscale);
  }

  // scores: per (b,h) GEMM (1025 x 1025 x 64) -> raw scores into attn region
  gemm_kernel<<<dim3(17, 17, 128), 256, 0, stream>>>(
      qh, kh, attn,
      1025, 1025, 64, 8,
      512LL, 1LL, 524800LL, 64LL,
      512LL, 1LL, 524800LL, 64LL,
      1025LL, 8405000LL, 1050625LL,
      nullptr, nullptr, 0.f);

  softmax_kernel<<<dim3(131200, 1, 1), 256, 0, stream>>>(attn);

  // ctx: per (b,h) GEMM (1025 x 64 x 1025)
  gemm_kernel<<<dim3(17, 1, 128), 256, 0, stream>>>(
      attn, vh, ctx,
      1025, 64, 1025, 8,
      1025LL, 1LL, 8405000LL, 1050625LL,
      1LL, 512LL, 524800LL, 64LL,
      512LL, 524800LL, 64LL,
      nullptr, nullptr, 0.f);

  // out projection: (B*F=16400 x 1024 x 512)
  gemm_kernel<<<dim3(257, 16, 1), 256, 0, stream>>>(
      ctx, Wo, yb,
      16400, 1024, 512, 1,
      512LL, 1LL, 0LL, 0LL,
      512LL, 1LL, 0LL, 0LL,
      1024LL, 0LL, 0LL,
      bo, nullptr, 0.f);

  irfft_kernel<<<dim3(512, 16, 1), 256, 0, stream>>>(yb, outp);
}

// Round 2
// 2821.463 us; speedup vs baseline: 1.9176x; 1.9176x over previous
//
#include <hip/hip_runtime.h>
#include <math.h>

#define FL 1025

typedef __bf16 bf16x8 __attribute__((ext_vector_type(8)));
typedef float  f32x4  __attribute__((ext_vector_type(4)));

static __device__ __forceinline__ unsigned short f2bf(float f) {
  union { __bf16 b; unsigned short s; } y; y.b = (__bf16)f; return y.s;
}
static __device__ __forceinline__ float bf2f(unsigned short s) {
  union { __bf16 b; unsigned short s; } y; y.s = s; return (float)y.b;
}

// ---------------------------------------------------------------------------
// In-LDS radix-2 DIT FFT, 2048 points, 256 threads (verified round 1).
static __device__ __forceinline__ void fft2048_stages(float* re, float* im, int tid, int dir) {
  for (int len = 2; len <= 2048; len <<= 1) {
    int half = len >> 1;
    __syncthreads();
    for (int t = tid; t < 1024; t += 256) {
      int j  = t & (half - 1);
      int i0 = ((t & ~(half - 1)) << 1) | j;
      int i1 = i0 + half;
      float ang = (2.0f * (float)j) / (float)len;
      float wr = cospif(ang);
      float s  = sinpif(ang);
      float wi = (dir > 0) ? s : -s;
      float vr = re[i1], vi = im[i1];
      float tr = vr * wr - vi * wi;
      float ti = vr * wi + vi * wr;
      float ur = re[i0], ui = im[i0];
      re[i0] = ur + tr; im[i0] = ui + ti;
      re[i1] = ur - tr; im[i1] = ui - ti;
    }
  }
  __syncthreads();
}

__global__ __launch_bounds__(256) void rfft_kernel(const float* __restrict__ x,
                                                   float* __restrict__ QF) {
  __shared__ float re[2048];
  __shared__ float im[2048];
  int c = blockIdx.x, b = blockIdx.y, tid = threadIdx.x;
  const float* xp = x + (long long)b * 2048 * 512 + c;
  for (int l = tid; l < 2048; l += 256) {
    int r = __brev((unsigned)l) >> 21;
    re[r] = xp[(long long)l * 512];
    im[r] = 0.f;
  }
  fft2048_stages(re, im, tid, -1);
  float* outRe = QF + ((long long)b * 1024 + c) * FL;
  float* outIm = QF + ((long long)b * 1024 + 512 + c) * FL;
  for (int f = tid; f < FL; f += 256) { outRe[f] = re[f]; outIm[f] = im[f]; }
}

__global__ __launch_bounds__(256) void irfft_kernel(const float* __restrict__ y,
                                                    float* __restrict__ out) {
  __shared__ float nre[FL];
  __shared__ float nim[FL];
  __shared__ float re[2048];
  __shared__ float im[2048];
  int d = blockIdx.x, b = blockIdx.y, tid = threadIdx.x;
  const float* yp = y + (long long)b * FL * 1024 + 2 * d;
  for (int f = tid; f < FL; f += 256) {
    nre[f] = yp[(long long)f * 1024];
    nim[f] = yp[(long long)f * 1024 + 1];
  }
  __syncthreads();
  for (int i = tid; i < 2048; i += 256) {
    int j = __brev((unsigned)i) >> 21;
    float r, mi;
    if (j <= 1024) { r = nre[j];        mi =  nim[j]; }
    else           { r = nre[2048 - j]; mi = -nim[2048 - j]; }
    re[i] = r; im[i] = mi;
  }
  fft2048_stages(re, im, tid, +1);
  float* op = out + (long long)b * 2048 * 512 + d;
  const float sc = 1.0f / 2048.0f;
  for (int l = tid; l < 2048; l += 256) op[(long long)l * 512] = re[l] * sc;
}

// ---------------------------------------------------------------------------
// MFMA GEMM: C[m,n] = sum_k A[m][k]*B[n][k], fp32 in/out, bf16 split compute.
// A,B are k-contiguous with row strides sAm/sBn. TERMS=3: hi*hi+hi*lo+lo*hi.
// BM=128 fixed, BK=32, 256 threads (4 waves); wave tile 64 x (BN/2).
template<int BN, int TERMS>
__global__ __launch_bounds__(256) void mfma_gemm(
    const float* __restrict__ A, const float* __restrict__ B, float* __restrict__ C,
    int M, int N, int K, int Kpad, int HB,
    long long sAm, long long sAb, long long sAh,
    long long sBn, long long sBb, long long sBh,
    long long sCm, long long sCb, long long sCh,
    const float* __restrict__ bias, const float* __restrict__ vvec, float uscale) {
  constexpr int BM = 128, LDH = 40;
  constexpr int NT = BN / 32;
  __shared__ __bf16 Ah[BM][LDH];
  __shared__ __bf16 Bh[BN][LDH];
  __shared__ __bf16 Al[(TERMS > 1) ? BM : 1][(TERMS > 1) ? LDH : 1];
  __shared__ __bf16 Bl[(TERMS > 1) ? BN : 1][(TERMS > 1) ? LDH : 1];

  int tid = threadIdx.x;
  int wid = tid >> 6, lane = tid & 63;
  int lrow = lane & 15, quad = lane >> 4;
  int m0 = blockIdx.x * BM, n0 = blockIdx.y * BN;
  int z = blockIdx.z;
  int bb = z / HB, hh = z - bb * HB;
  const float* Ab = A + (long long)bb * sAb + (long long)hh * sAh;
  const float* Bb = B + (long long)bb * sBb + (long long)hh * sBh;
  float* Cb = C + (long long)bb * sCb + (long long)hh * sCh;
  bool alA = (((((size_t)Ab) | ((size_t)(sAm * 4))) & 15) == 0);
  bool alB = (((((size_t)Bb) | ((size_t)(sBn * 4))) & 15) == 0);

  int wm0 = (wid & 1) * 64;
  int wn0 = (wid >> 1) * (BN / 2);

  f32x4 acc[4][NT];
#pragma unroll
  for (int i = 0; i < 4; i++)
#pragma unroll
    for (int j = 0; j < NT; j++) acc[i][j] = (f32x4){0.f, 0.f, 0.f, 0.f};

#define LDFRAG(arr, r, out) { \
    const __bf16* _p = &arr[r][quad * 8]; \
    union { uint2 q[2]; bf16x8 v; } _u; \
    _u.q[0] = *(const uint2*)_p; _u.q[1] = *(const uint2*)(_p + 4); \
    out = _u.v; }

  for (int k0 = 0; k0 < Kpad; k0 += 32) {
    // ---- stage A (BM x 32) ----
#pragma unroll
    for (int c = tid; c < BM * 4; c += 256) {
      int row = c >> 2, kc = (c & 3) << 3;
      int mg = min(m0 + row, M - 1);
      const float* src = Ab + (long long)mg * sAm + k0 + kc;
      float v[8];
      if (alA && (k0 + kc + 8 <= K)) {
        float4 f0 = *(const float4*)src;
        float4 f1 = *(const float4*)(src + 4);
        v[0] = f0.x; v[1] = f0.y; v[2] = f0.z; v[3] = f0.w;
        v[4] = f1.x; v[5] = f1.y; v[6] = f1.z; v[7] = f1.w;
      } else {
#pragma unroll
        for (int j = 0; j < 8; j++) { int kk = k0 + kc + j; v[j] = (kk < K) ? src[j] : 0.f; }
      }
      unsigned hu[4], lu[4];
#pragma unroll
      for (int p = 0; p < 4; p++) {
        unsigned short h0 = f2bf(v[2 * p]), h1 = f2bf(v[2 * p + 1]);
        hu[p] = (unsigned)h0 | ((unsigned)h1 << 16);
        if constexpr (TERMS > 1) {
          float r0 = v[2 * p]     - bf2f(h0);
          float r1 = v[2 * p + 1] - bf2f(h1);
          lu[p] = (unsigned)f2bf(r0) | ((unsigned)f2bf(r1) << 16);
        }
      }
      uint2* dh = (uint2*)&Ah[row][kc];
      dh[0] = make_uint2(hu[0], hu[1]); dh[1] = make_uint2(hu[2], hu[3]);
      if constexpr (TERMS > 1) {
        uint2* dl = (uint2*)&Al[row][kc];
        dl[0] = make_uint2(lu[0], lu[1]); dl[1] = make_uint2(lu[2], lu[3]);
      }
    }
    // ---- stage B (BN x 32); B sources are K-padded (no masking needed) ----
#pragma unroll
    for (int c = tid; c < BN * 4; c += 256) {
      int row = c >> 2, kc = (c & 3) << 3;
      int ng = min(n0 + row, N - 1);
      const float* src = Bb + (long long)ng * sBn + k0 + kc;
      float v[8];
      if (alB) {
        float4 f0 = *(const float4*)src;
        float4 f1 = *(const float4*)(src + 4);
        v[0] = f0.x; v[1] = f0.y; v[2] = f0.z; v[3] = f0.w;
        v[4] = f1.x; v[5] = f1.y; v[6] = f1.z; v[7] = f1.w;
      } else {
#pragma unroll
        for (int j = 0; j < 8; j++) v[j] = src[j];
      }
      unsigned hu[4], lu[4];
#pragma unroll
      for (int p = 0; p < 4; p++) {
        unsigned short h0 = f2bf(v[2 * p]), h1 = f2bf(v[2 * p + 1]);
        hu[p] = (unsigned)h0 | ((unsigned)h1 << 16);
        if constexpr (TERMS > 1) {
          float r0 = v[2 * p]     - bf2f(h0);
          float r1 = v[2 * p + 1] - bf2f(h1);
          lu[p] = (unsigned)f2bf(r0) | ((unsigned)f2bf(r1) << 16);
        }
      }
      uint2* dh = (uint2*)&Bh[row][kc];
      dh[0] = make_uint2(hu[0], hu[1]); dh[1] = make_uint2(hu[2], hu[3]);
      if constexpr (TERMS > 1) {
        uint2* dl = (uint2*)&Bl[row][kc];
        dl[0] = make_uint2(lu[0], lu[1]); dl[1] = make_uint2(lu[2], lu[3]);
      }
    }
    __syncthreads();

    bf16x8 bhf[NT], blf[NT];
#pragma unroll
    for (int nt = 0; nt < NT; nt++) {
      int r = wn0 + nt * 16 + lrow;
      LDFRAG(Bh, r, bhf[nt]);
      if constexpr (TERMS > 1) LDFRAG(Bl, r, blf[nt]);
    }
#pragma unroll
    for (int mt = 0; mt < 4; mt++) {
      int r = wm0 + mt * 16 + lrow;
      bf16x8 ahf, alf;
      LDFRAG(Ah, r, ahf);
      if constexpr (TERMS > 1) LDFRAG(Al, r, alf);
#pragma unroll
      for (int nt = 0; nt < NT; nt++) {
        acc[mt][nt] = __builtin_amdgcn_mfma_f32_16x16x32_bf16(ahf, bhf[nt], acc[mt][nt], 0, 0, 0);
        if constexpr (TERMS > 1) {
          acc[mt][nt] = __builtin_amdgcn_mfma_f32_16x16x32_bf16(ahf, blf[nt], acc[mt][nt], 0, 0, 0);
          acc[mt][nt] = __builtin_amdgcn_mfma_f32_16x16x32_bf16(alf, bhf[nt], acc[mt][nt], 0, 0, 0);
        }
      }
    }
    __syncthreads();
  }
#undef LDFRAG

  // epilogue: D row=(quad*4+reg), col=lane&15  [verified m89]
#pragma unroll
  for (int mt = 0; mt < 4; mt++) {
#pragma unroll
    for (int nt = 0; nt < NT; nt++) {
      int gn = n0 + wn0 + nt * 16 + lrow;
      if (gn < N) {
        float bn = bias ? bias[gn] : 0.f;
        float vn = vvec ? vvec[gn] : 0.f;
        int gmb = m0 + wm0 + mt * 16 + quad * 4;
#pragma unroll
        for (int r = 0; r < 4; r++) {
          int gm = gmb + r;
          if (gm < M) {
            float val = acc[mt][nt][r] + bn + uscale * (float)gm * vn;
            Cb[(long long)gm * sCm + gn] = val;
          }
        }
      }
    }
  }
}

// ---------------------------------------------------------------------------
// softmax over 1025 with scale 1/8 (verified round 1), in-place on d_out attn.
__global__ __launch_bounds__(256) void softmax_kernel(float* __restrict__ attn) {
  long long row = blockIdx.x;
  float* p = attn + row * FL;
  int tid = threadIdx.x;
  float x[5];
  float mx = -INFINITY;
#pragma unroll
  for (int k = 0; k < 5; k++) {
    int i = tid + 256 * k;
    x[k] = (i < FL) ? p[i] * 0.125f : -INFINITY;
    mx = fmaxf(mx, x[k]);
  }
  for (int o = 32; o; o >>= 1) mx = fmaxf(mx, __shfl_xor(mx, o, 64));
  __shared__ float sm[4];
  __shared__ float ssum[4];
  int wid = tid >> 6;
  if ((tid & 63) == 0) sm[wid] = mx;
  __syncthreads();
  mx = fmaxf(fmaxf(sm[0], sm[1]), fmaxf(sm[2], sm[3]));
  float sum = 0.f;
#pragma unroll
  for (int k = 0; k < 5; k++) {
    int i = tid + 256 * k;
    x[k] = (i < FL) ? expf(x[k] - mx) : 0.f;
    sum += x[k];
  }
  for (int o = 32; o; o >>= 1) sum += __shfl_xor(sum, o, 64);
  if ((tid & 63) == 0) ssum[wid] = sum;
  __syncthreads();
  sum = ssum[0] + ssum[1] + ssum[2] + ssum[3];
  float rinv = 1.0f / sum;
#pragma unroll
  for (int k = 0; k < 5; k++) {
    int i = tid + 256 * k;
    if (i < FL) p[i] = x[k] * rinv;
  }
}

// ---------------------------------------------------------------------------
// QF [b][k=1024][f=1025] -> QFT [b][f=1025][k=1024]  (32x32 LDS transpose)
__global__ __launch_bounds__(256) void transpose_qf(const float* __restrict__ QF,
                                                    float* __restrict__ QFT) {
  __shared__ float t[32][33];
  int b = blockIdx.z;
  int f0 = blockIdx.x * 32, k0 = blockIdx.y * 32;
  int tx = threadIdx.x & 31, ty = threadIdx.x >> 5;
  for (int i = ty; i < 32; i += 8) {
    int f = f0 + tx, k = k0 + i;
    t[i][tx] = (f < FL) ? QF[((long long)b * 1024 + k) * FL + f] : 0.f;
  }
  __syncthreads();
  for (int i = ty; i < 32; i += 8) {
    int f = f0 + i, k = k0 + tx;
    if (f < FL) QFT[((long long)b * FL + f) * 1024 + k] = t[tx][i];
  }
}

// vh [b][s=1025][512] -> vhT [b][h][d=64][s=1056], zero pad s>=1025
__global__ __launch_bounds__(256) void transpose_vh(const float* __restrict__ vh,
                                                    float* __restrict__ vhT) {
  __shared__ float t[32][33];
  int z = blockIdx.z;
  int b = z >> 3, h = z & 7;
  int s0 = blockIdx.x * 32, d0 = blockIdx.y * 32;
  int tx = threadIdx.x & 31, ty = threadIdx.x >> 5;
  for (int i = ty; i < 32; i += 8) {
    int s = s0 + i, d = d0 + tx;
    t[i][tx] = (s < FL) ? vh[((long long)b * FL + s) * 512 + h * 64 + d] : 0.f;
  }
  __syncthreads();
  for (int i = ty; i < 32; i += 8) {
    int s = s0 + tx, d = d0 + i;
    vhT[((long long)z * 64 + d) * 1056 + s] = t[tx][i];
  }
}

// Wt[t][o=512][k=1024]: k<512 -> W[o][k][0], else W[o][k-512][1]
__global__ __launch_bounds__(256) void pack_w(const float* __restrict__ Wq,
                                              const float* __restrict__ Wk,
                                              const float* __restrict__ Wv,
                                              float* __restrict__ Wt) {
  int idx = blockIdx.x * 256 + threadIdx.x;   // o*1024 + k
  const float* W = (blockIdx.y == 0) ? Wq : (blockIdx.y == 1) ? Wk : Wv;
  int o = idx >> 10, k = idx & 1023;
  int c = k & 511, j = k >> 9;
  Wt[(long long)blockIdx.y * 524288 + idx] = W[(long long)o * 1536 + c * 3 + j];
}

__global__ __launch_bounds__(256) void wf_kernel(const float* __restrict__ Wq,
                                                 const float* __restrict__ Wk,
                                                 const float* __restrict__ Wv,
                                                 float* __restrict__ wf) {
  int o = blockIdx.x * 256 + threadIdx.x;
  if (o >= 512) return;
  const float* W = (blockIdx.y == 0) ? Wq : (blockIdx.y == 1) ? Wk : Wv;
  float s = 0.f;
  for (int c = 0; c < 512; c++) s += W[(long long)o * 1536 + c * 3 + 2];
  wf[blockIdx.y * 512 + o] = s;
}

// ---------------------------------------------------------------------------
extern "C" void kernel_launch(void* const* d_in, const int* in_sizes, int n_in,
                              void* d_out, int out_size, void* d_ws, size_t ws_size,
                              hipStream_t stream) {
  (void)in_sizes; (void)n_in; (void)out_size; (void)ws_size;
  const float* q  = (const float*)d_in[0];
  const float* k  = (const float*)d_in[1];
  const float* v  = (const float*)d_in[2];
  const float* Wq = (const float*)d_in[3];
  const float* bq = (const float*)d_in[4];
  const float* Wk = (const float*)d_in[5];
  const float* bk = (const float*)d_in[6];
  const float* Wv = (const float*)d_in[7];
  const float* bv = (const float*)d_in[8];
  const float* Wo = (const float*)d_in[9];
  const float* bo = (const float*)d_in[10];

  float* outp = (float*)d_out;                          // (16, 2048, 512)
  float* attn = outp + (long long)16 * 2048 * 512;      // (16, 8, 1025, 1025)

  float* ws  = (float*)d_ws;
  float* QF  = ws;                        // 16,793,600
  float* QFT = QF  + 16793600;            // 16,793,600
  float* Wt  = QFT + 16793600;            //  1,572,864
  float* qh  = Wt  + 1572864;             //  8,396,800
  float* kh  = qh  + 8396800;             //  8,396,800
  float* vh  = kh  + 8396800;             //  8,396,800
  float* wf  = vh  + 8396800;             //  1,536
  float* vhT = QF;                        //  8,650,752  (QF dead by then)
  float* ctx = QFT;                       //  8,396,800  (QFT dead by then)
  float* yb  = qh;                        // 16,793,600  (qh+kh dead by then)

  pack_w<<<dim3(2048, 3, 1), 256, 0, stream>>>(Wq, Wk, Wv, Wt);
  wf_kernel<<<dim3(2, 3, 1), 256, 0, stream>>>(Wq, Wk, Wv, wf);

  const float uscale = 1.0f / 2048.0f;
  const float* xs[3] = {q, k, v};
  const float* bs[3] = {bq, bk, bv};
  float* hs[3] = {qh, kh, vh};
  for (int t = 0; t < 3; t++) {
    rfft_kernel<<<dim3(512, 16, 1), 256, 0, stream>>>(xs[t], QF);
    transpose_qf<<<dim3(33, 32, 16), 256, 0, stream>>>(QF, QFT);
    // proj: (1025 x 512 x 1024) per b, split-bf16 (3 terms)
    mfma_gemm<128, 3><<<dim3(9, 4, 16), 256, 0, stream>>>(
        QFT, Wt + (long long)t * 524288, hs[t],
        1025, 512, 1024, 1024, 1,
        1024LL, 1049600LL, 0LL,
        1024LL, 0LL, 0LL,
        512LL, 524800LL, 0LL,
        bs[t], wf + t * 512, uscale);
  }

  // scores: (1025 x 1025 x 64) per (b,h), split-bf16 -> raw scores into attn
  mfma_gemm<128, 3><<<dim3(9, 9, 128), 256, 0, stream>>>(
      qh, kh, attn,
      1025, 1025, 64, 64, 8,
      512LL, 524800LL, 64LL,
      512LL, 524800LL, 64LL,
      1025LL, 8405000LL, 1050625LL,
      nullptr, nullptr, 0.f);

  softmax_kernel<<<dim3(131200, 1, 1), 256, 0, stream>>>(attn);

  transpose_vh<<<dim3(33, 2, 128), 256, 0, stream>>>(vh, vhT);

  // ctx: (1025 x 64 x 1025, Kpad 1056) per (b,h), 1-term bf16
  mfma_gemm<64, 1><<<dim3(9, 1, 128), 256, 0, stream>>>(
      attn, vhT, ctx,
      1025, 64, 1025, 1056, 8,
      1025LL, 8405000LL, 1050625LL,
      1056LL, 540672LL, 67584LL,
      512LL, 524800LL, 64LL,
      nullptr, nullptr, 0.f);

  // out projection: (16400 x 1024 x 512), 1-term bf16; Wo already [n][k]
  mfma_gemm<128, 1><<<dim3(129, 8, 1), 256, 0, stream>>>(
      ctx, Wo, yb,
      16400, 1024, 512, 512, 1,
      512LL, 0LL, 0LL,
      512LL, 0LL, 0LL,
      1024LL, 0LL, 0LL,
      bo, nullptr, 0.f);

  irfft_kernel<<<dim3(512, 16, 1), 256, 0, stream>>>(yb, outp);
}

// Round 3
// 2171.205 us; speedup vs baseline: 2.4919x; 1.2995x over previous
//
#include <hip/hip_runtime.h>
#include <math.h>

#define FL 1025

typedef __bf16 bf16x8 __attribute__((ext_vector_type(8)));
typedef float  f32x4  __attribute__((ext_vector_type(4)));

static __device__ __forceinline__ bf16x8 ldfrag(const __bf16* p) {
  union { uint4 q; bf16x8 v; } u;
  u.q = *(const uint4*)p;
  return u.v;
}
static __device__ __forceinline__ float fexp(float x) { return __expf(x); }

// ---------------------------------------------------------------------------
// In-LDS radix-2 DIT FFT, 2048 points, 256 threads (verified rounds 1-2).
static __device__ __forceinline__ void fft2048_stages(float* re, float* im, int tid, int dir) {
  for (int len = 2; len <= 2048; len <<= 1) {
    int half = len >> 1;
    __syncthreads();
    for (int t = tid; t < 1024; t += 256) {
      int j  = t & (half - 1);
      int i0 = ((t & ~(half - 1)) << 1) | j;
      int i1 = i0 + half;
      float ang = (2.0f * (float)j) / (float)len;
      float wr = cospif(ang);
      float s  = sinpif(ang);
      float wi = (dir > 0) ? s : -s;
      float vr = re[i1], vi = im[i1];
      float tr = vr * wr - vi * wi;
      float ti = vr * wi + vi * wr;
      float ur = re[i0], ui = im[i0];
      re[i0] = ur + tr; im[i0] = ui + ti;
      re[i1] = ur - tr; im[i1] = ui - ti;
    }
  }
  __syncthreads();
}

// rfft of one (b,c) row of xT (contiguous loads). QF[b][k][f] planes.
__global__ __launch_bounds__(256) void rfft_kernel(const float* __restrict__ xT,
                                                   float* __restrict__ QF) {
  __shared__ float re[2048];
  __shared__ float im[2048];
  int c = blockIdx.x, b = blockIdx.y, tid = threadIdx.x;
  const float* xp = xT + ((long long)b * 512 + c) * 2048;
  float4 a0 = *(const float4*)(xp + tid * 8);
  float4 a1 = *(const float4*)(xp + tid * 8 + 4);
  float v[8] = {a0.x, a0.y, a0.z, a0.w, a1.x, a1.y, a1.z, a1.w};
#pragma unroll
  for (int j = 0; j < 8; j++) {
    int l = tid * 8 + j;
    int r = __brev((unsigned)l) >> 21;
    re[r] = v[j];
    im[r] = 0.f;
  }
  fft2048_stages(re, im, tid, -1);
  float* outRe = QF + ((long long)b * 1024 + c) * FL;
  float* outIm = QF + ((long long)b * 1024 + 512 + c) * FL;
  for (int f = tid; f < FL; f += 256) { outRe[f] = re[f]; outIm[f] = im[f]; }
}

// irfft (unchanged from round 2)
__global__ __launch_bounds__(256) void irfft_kernel(const float* __restrict__ y,
                                                    float* __restrict__ out) {
  __shared__ float nre[FL];
  __shared__ float nim[FL];
  __shared__ float re[2048];
  __shared__ float im[2048];
  int d = blockIdx.x, b = blockIdx.y, tid = threadIdx.x;
  const float* yp = y + (long long)b * FL * 1024 + 2 * d;
  for (int f = tid; f < FL; f += 256) {
    nre[f] = yp[(long long)f * 1024];
    nim[f] = yp[(long long)f * 1024 + 1];
  }
  __syncthreads();
  for (int i = tid; i < 2048; i += 256) {
    int j = __brev((unsigned)i) >> 21;
    float r, mi;
    if (j <= 1024) { r = nre[j];        mi =  nim[j]; }
    else           { r = nre[2048 - j]; mi = -nim[2048 - j]; }
    re[i] = r; im[i] = mi;
  }
  fft2048_stages(re, im, tid, +1);
  float* op = out + (long long)b * 2048 * 512 + d;
  const float sc = 1.0f / 2048.0f;
  for (int l = tid; l < 2048; l += 256) op[(long long)l * 512] = re[l] * sc;
}

// ---------------------------------------------------------------------------
// x (b, 2048, 512) -> xT (b, 512, 2048), 3 inputs in one launch.
__global__ __launch_bounds__(256) void transpose_x(const float* __restrict__ q,
                                                   const float* __restrict__ k,
                                                   const float* __restrict__ v,
                                                   float* __restrict__ xT) {
  __shared__ float t[32][33];
  int z = blockIdx.z;
  int ti = z >> 4, b = z & 15;
  const float* x = (ti == 0) ? q : (ti == 1) ? k : v;
  int l0 = blockIdx.x * 32, c0 = blockIdx.y * 32;
  int tx = threadIdx.x & 31, ty = threadIdx.x >> 5;
  for (int i = ty; i < 32; i += 8)
    t[i][tx] = x[((long long)b * 2048 + l0 + i) * 512 + c0 + tx];
  __syncthreads();
  float* dst = xT + ((long long)ti * 16 + b) * 512 * 2048;
  for (int i = ty; i < 32; i += 8)
    dst[((long long)(c0 + i)) * 2048 + l0 + tx] = t[tx][i];
}

// QF [b][k=1024][f=1025] fp32 -> split bf16 planes QFT_h/l [b][f][1024]
__global__ __launch_bounds__(256) void qsplit(const float* __restrict__ QF,
                                              __bf16* __restrict__ Qh,
                                              __bf16* __restrict__ Ql) {
  __shared__ float t[32][33];
  int b = blockIdx.z;
  int f0 = blockIdx.x * 32, k0 = blockIdx.y * 32;
  int tx = threadIdx.x & 31, ty = threadIdx.x >> 5;
  for (int i = ty; i < 32; i += 8) {
    int f = f0 + tx;
    t[i][tx] = (f < FL) ? QF[((long long)b * 1024 + k0 + i) * FL + f] : 0.f;
  }
  __syncthreads();
  for (int i = ty; i < 32; i += 8) {
    int f = f0 + i;
    if (f < FL) {
      float v = t[tx][i];
      __bf16 h = (__bf16)v;
      long long o = ((long long)b * FL + f) * 1024 + k0 + tx;
      Qh[o] = h;
      Ql[o] = (__bf16)(v - (float)h);
    }
  }
}

// vh bf16 [b][s=1025][512] -> vhT bf16 [(b,h)][d=64][s=1152], zero-pad s>=1025
__global__ __launch_bounds__(256) void transpose_vh(const __bf16* __restrict__ vh,
                                                    __bf16* __restrict__ vhT) {
  __shared__ __bf16 t[32][33];
  int z = blockIdx.z;
  int b = z >> 3, h = z & 7;
  int s0 = blockIdx.x * 32, d0 = blockIdx.y * 32;
  int tx = threadIdx.x & 31, ty = threadIdx.x >> 5;
  for (int i = ty; i < 32; i += 8) {
    int s = s0 + i;
    t[i][tx] = (s < FL) ? vh[((long long)b * FL + s) * 512 + h * 64 + d0 + tx] : (__bf16)0.f;
  }
  __syncthreads();
  for (int i = ty; i < 32; i += 8)
    vhT[((long long)z * 64 + d0 + i) * 1152 + s0 + tx] = t[tx][i];
}

// W (512, 512, 3) -> split bf16 Wt_h/l [t][o=512][k=1024]
__global__ __launch_bounds__(256) void pack_w(const float* __restrict__ Wq,
                                              const float* __restrict__ Wk,
                                              const float* __restrict__ Wv,
                                              __bf16* __restrict__ Wh,
                                              __bf16* __restrict__ Wl) {
  int idx = blockIdx.x * 256 + threadIdx.x;   // o*1024 + k
  const float* W = (blockIdx.y == 0) ? Wq : (blockIdx.y == 1) ? Wk : Wv;
  int o = idx >> 10, kk = idx & 1023;
  int c = kk & 511, j = kk >> 9;
  float v = W[(long long)o * 1536 + c * 3 + j];
  __bf16 h = (__bf16)v;
  long long oo = (long long)blockIdx.y * 524288 + idx;
  Wh[oo] = h;
  Wl[oo] = (__bf16)(v - (float)h);
}

// Wo fp32 (1024,512) -> bf16 hi plane
__global__ __launch_bounds__(256) void pack_wo(const float* __restrict__ Wo,
                                               __bf16* __restrict__ Woh) {
  int idx = blockIdx.x * 256 + threadIdx.x;
  Woh[idx] = (__bf16)Wo[idx];
}

__global__ __launch_bounds__(256) void wf_kernel(const float* __restrict__ Wq,
                                                 const float* __restrict__ Wk,
                                                 const float* __restrict__ Wv,
                                                 float* __restrict__ wf) {
  int o = blockIdx.x * 256 + threadIdx.x;
  if (o >= 512) return;
  const float* W = (blockIdx.y == 0) ? Wq : (blockIdx.y == 1) ? Wk : Wv;
  float s = 0.f;
  for (int c = 0; c < 512; c++) s += W[(long long)o * 1536 + c * 3 + 2];
  wf[blockIdx.y * 512 + o] = s;
}

// ---------------------------------------------------------------------------
// Pre-split MFMA GEMM: C[m,n] = sum_k A[m][k]*B[n][k]. Operands are bf16
// hi/lo planes, k-contiguous. TERMS=3: hh+hl+lh. WOUT: 0 fp32, 1 split bf16,
// 2 bf16 hi. 128x128 tile, BK=32, 256 thr, wave tile 64x64.
template<int TERMS, int WOUT>
__global__ __launch_bounds__(256) void mfma_gemm2(
    const __bf16* __restrict__ Ah_g, const __bf16* __restrict__ Al_g,
    const __bf16* __restrict__ Bh_g, const __bf16* __restrict__ Bl_g,
    float* __restrict__ C, __bf16* __restrict__ Ch, __bf16* __restrict__ Cl,
    int M, int N, int K,
    long long sAm, long long sAb, long long sBn, long long sBb,
    long long sCm, long long sCb,
    const float* __restrict__ bias, const float* __restrict__ vvec, float uscale) {
  constexpr int PL = (TERMS > 1) ? 2 : 1;
  __shared__ __bf16 As[PL][128][40];
  __shared__ __bf16 Bs[PL][128][40];
  int tid = threadIdx.x;
  int wid = tid >> 6, lane = tid & 63;
  int lrow = lane & 15, quad = lane >> 4;
  int m0 = blockIdx.x * 128, n0 = blockIdx.y * 128;
  int z = blockIdx.z;
  const __bf16* Abh = Ah_g + (long long)z * sAb;
  const __bf16* Abl = Al_g + (long long)z * sAb;
  const __bf16* Bbh = Bh_g + (long long)z * sBb;
  const __bf16* Bbl = Bl_g + (long long)z * sBb;

  int wm0 = (wid & 1) * 64, wn0 = (wid >> 1) * 64;
  int srow = tid >> 1, shalf = tid & 1;
  int arow = min(m0 + srow, M - 1);
  int brow = min(n0 + srow, N - 1);

  f32x4 acc[4][4];
#pragma unroll
  for (int i = 0; i < 4; i++)
#pragma unroll
    for (int j = 0; j < 4; j++) acc[i][j] = (f32x4){0.f, 0.f, 0.f, 0.f};

  for (int k0 = 0; k0 < K; k0 += 32) {
    {
      const __bf16* s = Abh + (long long)arow * sAm + k0 + shalf * 16;
      uint4* d = (uint4*)&As[0][srow][shalf * 16];
      d[0] = ((const uint4*)s)[0]; d[1] = ((const uint4*)s)[1];
      s = Bbh + (long long)brow * sBn + k0 + shalf * 16;
      d = (uint4*)&Bs[0][srow][shalf * 16];
      d[0] = ((const uint4*)s)[0]; d[1] = ((const uint4*)s)[1];
      if constexpr (TERMS > 1) {
        s = Abl + (long long)arow * sAm + k0 + shalf * 16;
        d = (uint4*)&As[1][srow][shalf * 16];
        d[0] = ((const uint4*)s)[0]; d[1] = ((const uint4*)s)[1];
        s = Bbl + (long long)brow * sBn + k0 + shalf * 16;
        d = (uint4*)&Bs[1][srow][shalf * 16];
        d[0] = ((const uint4*)s)[0]; d[1] = ((const uint4*)s)[1];
      }
    }
    __syncthreads();

    bf16x8 bh[4], bl[4];
#pragma unroll
    for (int nt = 0; nt < 4; nt++) {
      int r = wn0 + nt * 16 + lrow;
      bh[nt] = ldfrag(&Bs[0][r][quad * 8]);
      if constexpr (TERMS > 1) bl[nt] = ldfrag(&Bs[1][r][quad * 8]);
    }
#pragma unroll
    for (int mt = 0; mt < 4; mt++) {
      int r = wm0 + mt * 16 + lrow;
      bf16x8 ah = ldfrag(&As[0][r][quad * 8]);
      bf16x8 al;
      if constexpr (TERMS > 1) al = ldfrag(&As[1][r][quad * 8]);
#pragma unroll
      for (int nt = 0; nt < 4; nt++) {
        acc[mt][nt] = __builtin_amdgcn_mfma_f32_16x16x32_bf16(ah, bh[nt], acc[mt][nt], 0, 0, 0);
        if constexpr (TERMS > 1) {
          acc[mt][nt] = __builtin_amdgcn_mfma_f32_16x16x32_bf16(ah, bl[nt], acc[mt][nt], 0, 0, 0);
          acc[mt][nt] = __builtin_amdgcn_mfma_f32_16x16x32_bf16(al, bh[nt], acc[mt][nt], 0, 0, 0);
        }
      }
    }
    __syncthreads();
  }

#pragma unroll
  for (int mt = 0; mt < 4; mt++) {
#pragma unroll
    for (int nt = 0; nt < 4; nt++) {
      int gn = n0 + wn0 + nt * 16 + lrow;
      if (gn < N) {
        float bn = bias ? bias[gn] : 0.f;
        float vn = vvec ? vvec[gn] : 0.f;
        int gmb = m0 + wm0 + mt * 16 + quad * 4;
#pragma unroll
        for (int r = 0; r < 4; r++) {
          int gm = gmb + r;
          if (gm < M) {
            float val = acc[mt][nt][r] + bn + uscale * (float)gm * vn;
            long long o = (long long)z * sCb + (long long)gm * sCm + gn;
            if constexpr (WOUT == 0) C[o] = val;
            else if constexpr (WOUT == 1) {
              __bf16 h = (__bf16)val;
              Ch[o] = h; Cl[o] = (__bf16)(val - (float)h);
            } else Ch[o] = (__bf16)val;
          }
        }
      }
    }
  }
}

// ---------------------------------------------------------------------------
// Fused flash attention: per (b,h), 128-row Q tile, two-pass online softmax
// with exact recompute; writes normalized attn (fp32) and ctx (bf16).
// 512 threads = 8 waves; wave w owns rows w*16..w*16+15, full 128-col tiles.
static __device__ __forceinline__ void compute_S_tile(
    const __bf16 (*Kh)[72], const __bf16 (*Kl)[72],
    const bf16x8 (&qf)[2][2], int lrow, int quad, int n0, f32x4* sa) {
#pragma unroll
  for (int nt = 0; nt < 8; nt++) sa[nt] = (f32x4){0.f, 0.f, 0.f, 0.f};
#pragma unroll
  for (int kit = 0; kit < 2; kit++) {
#pragma unroll
    for (int nt = 0; nt < 8; nt++) {
      const __bf16* kp = &Kh[nt * 16 + lrow][kit * 32 + quad * 8];
      const __bf16* lp = &Kl[nt * 16 + lrow][kit * 32 + quad * 8];
      bf16x8 kh = ldfrag(kp);
      bf16x8 kl = ldfrag(lp);
      sa[nt] = __builtin_amdgcn_mfma_f32_16x16x32_bf16(qf[0][kit], kh, sa[nt], 0, 0, 0);
      sa[nt] = __builtin_amdgcn_mfma_f32_16x16x32_bf16(qf[0][kit], kl, sa[nt], 0, 0, 0);
      sa[nt] = __builtin_amdgcn_mfma_f32_16x16x32_bf16(qf[1][kit], kh, sa[nt], 0, 0, 0);
    }
  }
  // scale + column mask (identical in both passes)
#pragma unroll
  for (int nt = 0; nt < 8; nt++) {
    int gn = n0 + nt * 16 + lrow;
    bool ok = gn < FL;
#pragma unroll
    for (int r = 0; r < 4; r++) sa[nt][r] = ok ? sa[nt][r] * 0.125f : -INFINITY;
  }
}

__global__ __launch_bounds__(512) void flash_kernel(
    const __bf16* __restrict__ qh_h, const __bf16* __restrict__ qh_l,
    const __bf16* __restrict__ kh_h, const __bf16* __restrict__ kh_l,
    const __bf16* __restrict__ vhT,
    float* __restrict__ attn, __bf16* __restrict__ ctxb) {
  __shared__ __align__(16) char smem[54272];
  __bf16 (*Kh)[72]  = (__bf16 (*)[72])smem;
  __bf16 (*Kl)[72]  = (__bf16 (*)[72])(smem + 18432);
  __bf16 (*P)[136]  = (__bf16 (*)[136])smem;          // aliases Kh/Kl
  __bf16 (*Bv)[136] = (__bf16 (*)[136])(smem + 36864);

  int tid = threadIdx.x;
  int wid = tid >> 6, lane = tid & 63;
  int lrow = lane & 15, quad = lane >> 4;
  int f0 = blockIdx.x * 128;
  int z = blockIdx.z;
  int b = z >> 3, h = z & 7;

  // Q fragments (A-layout), loaded once from global
  bf16x8 qf[2][2];
  {
    int rowq = min(f0 + wid * 16 + lrow, FL - 1);
    long long base = ((long long)b * FL + rowq) * 512 + h * 64 + quad * 8;
#pragma unroll
    for (int kit = 0; kit < 2; kit++) {
      qf[0][kit] = ldfrag(qh_h + base + kit * 32);
      qf[1][kit] = ldfrag(qh_l + base + kit * 32);
    }
  }

  // staging indices for K tiles (both planes)
  int sp = tid >> 8, srw = (tid >> 1) & 127, shalf = tid & 1;
  const __bf16* ksrc0 = (sp ? kh_l : kh_h) + (long long)b * FL * 512 + h * 64 + shalf * 32;
  __bf16* kdst = (sp ? Kl[srw] : Kh[srw]) + shalf * 32;

  float m_i[4], l_i[4];
#pragma unroll
  for (int r = 0; r < 4; r++) { m_i[r] = -INFINITY; l_i[r] = 0.f; }

  f32x4 sa[8];

  // ---- pass 1: exact online (m, l) ----
  for (int nt0 = 0; nt0 < 9; nt0++) {
    __syncthreads();
    {
      int srowg = min(nt0 * 128 + srw, FL - 1);
      const __bf16* s = ksrc0 + (long long)srowg * 512;
#pragma unroll
      for (int u = 0; u < 4; u++) ((uint4*)kdst)[u] = ((const uint4*)s)[u];
    }
    __syncthreads();
    compute_S_tile(Kh, Kl, qf, lrow, quad, nt0 * 128, sa);
#pragma unroll
    for (int r = 0; r < 4; r++) {
      float mx = -INFINITY;
#pragma unroll
      for (int nt = 0; nt < 8; nt++) mx = fmaxf(mx, sa[nt][r]);
      for (int o = 1; o < 16; o <<= 1) mx = fmaxf(mx, __shfl_xor(mx, o, 64));
      float mn = fmaxf(m_i[r], mx);
      float al = fexp(m_i[r] - mn);
      float ps = 0.f;
#pragma unroll
      for (int nt = 0; nt < 8; nt++) ps += fexp(sa[nt][r] - mn);
      for (int o = 1; o < 16; o <<= 1) ps += __shfl_xor(ps, o, 64);
      l_i[r] = l_i[r] * al + ps;
      m_i[r] = mn;
    }
  }

  float rl[4];
#pragma unroll
  for (int r = 0; r < 4; r++) rl[r] = 1.0f / l_i[r];

  f32x4 oa[4];
#pragma unroll
  for (int j = 0; j < 4; j++) oa[j] = (f32x4){0.f, 0.f, 0.f, 0.f};

  // V staging indices
  int vrow = tid >> 3, voff = (tid & 7) * 16;
  const __bf16* vsrc0 = vhT + ((long long)z * 64 + vrow) * 1152 + voff;
  __bf16* vdst = &Bv[vrow][voff];

  // ---- pass 2: recompute S, emit attn, accumulate O = P*V ----
  float* attnz = attn + (long long)z * 1050625;
  for (int nt0 = 0; nt0 < 9; nt0++) {
    __syncthreads();
    {
      int srowg = min(nt0 * 128 + srw, FL - 1);
      const __bf16* s = ksrc0 + (long long)srowg * 512;
#pragma unroll
      for (int u = 0; u < 4; u++) ((uint4*)kdst)[u] = ((const uint4*)s)[u];
      const __bf16* vs = vsrc0 + nt0 * 128;
      ((uint4*)vdst)[0] = ((const uint4*)vs)[0];
      ((uint4*)vdst)[1] = ((const uint4*)vs)[1];
    }
    __syncthreads();
    compute_S_tile(Kh, Kl, qf, lrow, quad, nt0 * 128, sa);
    __syncthreads();   // all K reads done before P overwrites the same LDS
#pragma unroll
    for (int nt = 0; nt < 8; nt++) {
      int gn = nt0 * 128 + nt * 16 + lrow;
#pragma unroll
      for (int r = 0; r < 4; r++) {
        float p = fexp(sa[nt][r] - m_i[r]) * rl[r];
        int lm = wid * 16 + quad * 4 + r;
        int gm = f0 + lm;
        if (gm < FL && gn < FL) attnz[(long long)gm * FL + gn] = p;
        P[lm][nt * 16 + lrow] = (__bf16)p;
      }
    }
    // own-wave P rows; V staged under barrier; no extra barrier needed
#pragma unroll
    for (int kk = 0; kk < 4; kk++) {
      bf16x8 pf = ldfrag(&P[wid * 16 + lrow][kk * 32 + quad * 8]);
#pragma unroll
      for (int nto = 0; nto < 4; nto++) {
        bf16x8 vf = ldfrag(&Bv[nto * 16 + lrow][kk * 32 + quad * 8]);
        oa[nto] = __builtin_amdgcn_mfma_f32_16x16x32_bf16(pf, vf, oa[nto], 0, 0, 0);
      }
    }
  }

#pragma unroll
  for (int nto = 0; nto < 4; nto++) {
#pragma unroll
    for (int r = 0; r < 4; r++) {
      int gm = f0 + wid * 16 + quad * 4 + r;
      if (gm < FL)
        ctxb[((long long)b * FL + gm) * 512 + h * 64 + nto * 16 + lrow] = (__bf16)oa[nto][r];
    }
  }
}

// ---------------------------------------------------------------------------
extern "C" void kernel_launch(void* const* d_in, const int* in_sizes, int n_in,
                              void* d_out, int out_size, void* d_ws, size_t ws_size,
                              hipStream_t stream) {
  (void)in_sizes; (void)n_in; (void)out_size; (void)ws_size;
  const float* q  = (const float*)d_in[0];
  const float* k  = (const float*)d_in[1];
  const float* v  = (const float*)d_in[2];
  const float* Wq = (const float*)d_in[3];
  const float* bq = (const float*)d_in[4];
  const float* Wk = (const float*)d_in[5];
  const float* bk = (const float*)d_in[6];
  const float* Wv = (const float*)d_in[7];
  const float* bv = (const float*)d_in[8];
  const float* Wo = (const float*)d_in[9];
  const float* bo = (const float*)d_in[10];

  float* outp = (float*)d_out;
  float* attn = outp + (long long)16 * 2048 * 512;

  float* ws   = (float*)d_ws;
  float*  xT   = ws;                                  // 50,331,648 fl
  float*  QF   = xT + 50331648;                       // 16,793,600 fl
  __bf16* QFTh = (__bf16*)(QF + 16793600);            // 16,793,600 bf16
  __bf16* QFTl = QFTh + 16793600;                     // 16,793,600 bf16
  __bf16* Wth  = QFTl + 16793600;                     //  1,572,864 bf16
  __bf16* Wtl  = Wth + 1572864;
  float*  wf   = (float*)(Wtl + 1572864);             //      1,536 fl
  __bf16* qhh  = (__bf16*)(wf + 1536);                //  8,396,800 bf16 each
  __bf16* qhl  = qhh + 8396800;
  __bf16* khh  = qhl + 8396800;
  __bf16* khl  = khh + 8396800;
  __bf16* vhb  = khl + 8396800;
  __bf16* Woh  = vhb + 8396800;                       //    524,288 bf16
  __bf16* vhT  = QFTh;                                // alias (QFT dead)
  __bf16* ctx  = (__bf16*)QF;                         // alias (QF dead)
  float*  yb   = xT;                                  // alias (xT dead)

  transpose_x<<<dim3(64, 16, 48), 256, 0, stream>>>(q, k, v, xT);
  pack_w<<<dim3(2048, 3, 1), 256, 0, stream>>>(Wq, Wk, Wv, Wth, Wtl);
  pack_wo<<<dim3(2048, 1, 1), 256, 0, stream>>>(Wo, Woh);
  wf_kernel<<<dim3(2, 3, 1), 256, 0, stream>>>(Wq, Wk, Wv, wf);

  const float uscale = 1.0f / 2048.0f;
  const float* bs[3] = {bq, bk, bv};
  for (int t = 0; t < 3; t++) {
    rfft_kernel<<<dim3(512, 16, 1), 256, 0, stream>>>(
        xT + (long long)t * 16 * 512 * 2048, QF);
    qsplit<<<dim3(33, 32, 16), 256, 0, stream>>>(QF, QFTh, QFTl);
    if (t < 2) {
      __bf16* ch = (t == 0) ? qhh : khh;
      __bf16* cl = (t == 0) ? qhl : khl;
      mfma_gemm2<3, 1><<<dim3(9, 4, 16), 256, 0, stream>>>(
          QFTh, QFTl, Wth + (long long)t * 524288, Wtl + (long long)t * 524288,
          nullptr, ch, cl,
          1025, 512, 1024,
          1024LL, 1049600LL, 1024LL, 0LL, 512LL, 524800LL,
          bs[t], wf + t * 512, uscale);
    } else {
      mfma_gemm2<3, 2><<<dim3(9, 4, 16), 256, 0, stream>>>(
          QFTh, QFTl, Wth + (long long)t * 524288, Wtl + (long long)t * 524288,
          nullptr, vhb, nullptr,
          1025, 512, 1024,
          1024LL, 1049600LL, 1024LL, 0LL, 512LL, 524800LL,
          bs[t], wf + t * 512, uscale);
    }
  }

  transpose_vh<<<dim3(36, 2, 128), 256, 0, stream>>>(vhb, vhT);

  flash_kernel<<<dim3(9, 1, 128), 512, 0, stream>>>(
      qhh, qhl, khh, khl, vhT, attn, ctx);

  // out projection: (16400 x 1024 x 512), 1-term
  mfma_gemm2<1, 0><<<dim3(129, 8, 1), 256, 0, stream>>>(
      ctx, nullptr, Woh, nullptr,
      yb, nullptr, nullptr,
      16400, 1024, 512,
      512LL, 0LL, 512LL, 0LL, 1024LL, 0LL,
      bo, nullptr, 0.f);

  irfft_kernel<<<dim3(512, 16, 1), 256, 0, stream>>>(yb, outp);
}

// Round 4
// 1791.176 us; speedup vs baseline: 3.0206x; 1.2122x over previous
//
#include <hip/hip_runtime.h>
#include <math.h>

#define FL 1025

typedef __bf16 bf16x8 __attribute__((ext_vector_type(8)));
typedef float  f32x4  __attribute__((ext_vector_type(4)));

static __device__ __forceinline__ bf16x8 ldfrag(const __bf16* p) {
  union { uint4 q; bf16x8 v; } u;
  u.q = *(const uint4*)p;
  return u.v;
}
static __device__ __forceinline__ float fexp(float x) { return __expf(x); }

// ---------------------------------------------------------------------------
// In-LDS radix-2 DIT FFT, 2048 points, 256 threads (verified rounds 1-3).
static __device__ __forceinline__ void fft2048_stages(float* re, float* im, int tid, int dir) {
  for (int len = 2; len <= 2048; len <<= 1) {
    int half = len >> 1;
    __syncthreads();
    for (int t = tid; t < 1024; t += 256) {
      int j  = t & (half - 1);
      int i0 = ((t & ~(half - 1)) << 1) | j;
      int i1 = i0 + half;
      float ang = (2.0f * (float)j) / (float)len;
      float wr = cospif(ang);
      float s  = sinpif(ang);
      float wi = (dir > 0) ? s : -s;
      float vr = re[i1], vi = im[i1];
      float tr = vr * wr - vi * wi;
      float ti = vr * wi + vi * wr;
      float ur = re[i0], ui = im[i0];
      re[i0] = ur + tr; im[i0] = ui + ti;
      re[i1] = ur - tr; im[i1] = ui - ti;
    }
  }
  __syncthreads();
}

// Pair-packed rfft: channels (2c2, 2c2+1) via one complex FFT + Hermitian
// unpack. QF3[t*16+b][k=1024][f], row stride 1028 (16B-aligned rows).
__global__ __launch_bounds__(256) void rfft3_kernel(const float* __restrict__ xT,
                                                    float* __restrict__ QF3) {
  __shared__ float re[2048];
  __shared__ float im[2048];
  int c2 = blockIdx.x, b = blockIdx.y, t = blockIdx.z, tid = threadIdx.x;
  const float* pa = xT + (((long long)t * 16 + b) * 512 + 2 * c2) * 2048;
  const float* pb = pa + 2048;
  float4 a0 = *(const float4*)(pa + tid * 8);
  float4 a1 = *(const float4*)(pa + tid * 8 + 4);
  float4 b0 = *(const float4*)(pb + tid * 8);
  float4 b1 = *(const float4*)(pb + tid * 8 + 4);
  float va[8] = {a0.x, a0.y, a0.z, a0.w, a1.x, a1.y, a1.z, a1.w};
  float vb[8] = {b0.x, b0.y, b0.z, b0.w, b1.x, b1.y, b1.z, b1.w};
#pragma unroll
  for (int j = 0; j < 8; j++) {
    int l = tid * 8 + j;
    int r = __brev((unsigned)l) >> 21;
    re[r] = va[j];
    im[r] = vb[j];
  }
  fft2048_stages(re, im, tid, -1);
  float* base = QF3 + ((long long)t * 16 + b) * 1052672;
  for (int f = tid; f <= 1024; f += 256) {
    int g = (2048 - f) & 2047;
    float fr = re[f], fi = im[f], gr = re[g], gi = im[g];
    float Xar = 0.5f * (fr + gr), Xai = 0.5f * (fi - gi);
    float Xbr = 0.5f * (fi + gi), Xbi = 0.5f * (gr - fr);
    base[(long long)(2 * c2) * 1028 + f]       = Xar;
    base[(long long)(512 + 2 * c2) * 1028 + f] = Xai;
    base[(long long)(2 * c2 + 1) * 1028 + f]   = Xbr;
    base[(long long)(513 + 2 * c2) * 1028 + f] = Xbi;
  }
}

// Pair-packed irfft: output channels (2d2, 2d2+1) from ybT rows 4d2..4d2+3.
// Zeroes Im at DC/Nyquist (c2r semantics). float2 stores to out.
__global__ __launch_bounds__(256) void irfft3_kernel(const float* __restrict__ ybT,
                                                     float* __restrict__ out) {
  __shared__ float Yar[FL], Yai[FL], Ybr[FL], Ybi[FL];
  __shared__ float re[2048];
  __shared__ float im[2048];
  int d2 = blockIdx.x, b = blockIdx.y, tid = threadIdx.x;
  const float* yp = ybT + ((long long)b * 1024 + 4 * d2) * 1025;
  for (int f = tid; f <= 1024; f += 256) {
    Yar[f] = yp[f];
    Yai[f] = yp[1025 + f];
    Ybr[f] = yp[2050 + f];
    Ybi[f] = yp[3075 + f];
  }
  __syncthreads();
  if (tid == 0) { Yai[0] = 0.f; Yai[1024] = 0.f; Ybi[0] = 0.f; Ybi[1024] = 0.f; }
  __syncthreads();
  for (int i = tid; i < 2048; i += 256) {
    int j = __brev((unsigned)i) >> 21;
    float rr, ii;
    if (j <= 1024) { rr = Yar[j] - Ybi[j]; ii = Yai[j] + Ybr[j]; }
    else { int f = 2048 - j; rr = Yar[f] + Ybi[f]; ii = Ybr[f] - Yai[f]; }
    re[i] = rr; im[i] = ii;
  }
  fft2048_stages(re, im, tid, +1);
  float* op = out + (long long)b * 2048 * 512 + 2 * d2;
  const float sc = 1.0f / 2048.0f;
  for (int l = tid; l < 2048; l += 256) {
    float2 v = {re[l] * sc, im[l] * sc};
    *(float2*)(op + (long long)l * 512) = v;
  }
}

// ---------------------------------------------------------------------------
// x (b, 2048, 512) -> xT (b, 512, 2048), 3 inputs in one launch.
__global__ __launch_bounds__(256) void transpose_x(const float* __restrict__ q,
                                                   const float* __restrict__ k,
                                                   const float* __restrict__ v,
                                                   float* __restrict__ xT) {
  __shared__ float t[32][33];
  int z = blockIdx.z;
  int ti = z >> 4, b = z & 15;
  const float* x = (ti == 0) ? q : (ti == 1) ? k : v;
  int l0 = blockIdx.x * 32, c0 = blockIdx.y * 32;
  int tx = threadIdx.x & 31, ty = threadIdx.x >> 5;
  for (int i = ty; i < 32; i += 8)
    t[i][tx] = x[((long long)b * 2048 + l0 + i) * 512 + c0 + tx];
  __syncthreads();
  float* dst = xT + ((long long)ti * 16 + b) * 512 * 2048;
  for (int i = ty; i < 32; i += 8)
    dst[((long long)(c0 + i)) * 2048 + l0 + tx] = t[tx][i];
}

// ---------------------------------------------------------------------------
// One-shot setup: pack_w (split bf16), pack_wo, wf column sums, bias gather.
__global__ __launch_bounds__(256) void setup_pack(
    const float* __restrict__ Wq, const float* __restrict__ Wk,
    const float* __restrict__ Wv, const float* __restrict__ Wo,
    const float* __restrict__ bq, const float* __restrict__ bk,
    const float* __restrict__ bv,
    __bf16* __restrict__ Wth, __bf16* __restrict__ Wtl,
    __bf16* __restrict__ Woh, float* __restrict__ wf3, float* __restrict__ bias3) {
  int bx = blockIdx.x, tid = threadIdx.x;
  if (bx < 6144) {
    int e = bx * 256 + tid;               // 0 .. 1,572,863
    int t = e >> 19, local = e & 524287;
    const float* W = (t == 0) ? Wq : (t == 1) ? Wk : Wv;
    int o = local >> 10, kk = local & 1023;
    int c = kk & 511, j = kk >> 9;
    float v = W[(long long)o * 1536 + c * 3 + j];
    __bf16 h = (__bf16)v;
    Wth[e] = h;
    Wtl[e] = (__bf16)(v - (float)h);
  } else if (bx < 8192) {
    int e = (bx - 6144) * 256 + tid;      // 0 .. 524,287
    Woh[e] = (__bf16)Wo[e];
  } else if (bx < 8198) {
    int idx = (bx - 8192) * 256 + tid;    // 0 .. 1535
    int t = idx / 512, o = idx & 511;
    const float* W = (t == 0) ? Wq : (t == 1) ? Wk : Wv;
    float s = 0.f;
    for (int c = 0; c < 512; c++) s += W[(long long)o * 1536 + c * 3 + 2];
    wf3[idx] = s;
  } else {
    int idx = (bx - 8198) * 256 + tid;    // 0 .. 1535
    int t = idx / 512, o = idx & 511;
    bias3[idx] = (t == 0) ? bq[o] : (t == 1) ? bk[o] : bv[o];
  }
}

// ---------------------------------------------------------------------------
// Fused projection GEMM: A = QF3 (fp32, [k][f] layout, transposed+split in
// staging), B = Wt hi/lo planes. z = t*16+b. 3-term split compute.
// t<2 -> split bf16 qh/kh; t==2 -> vhT layout directly.
__global__ __launch_bounds__(256) void proj_gemm(
    const float* __restrict__ QF3,
    const __bf16* __restrict__ Wth, const __bf16* __restrict__ Wtl,
    const float* __restrict__ wf3, const float* __restrict__ bias3,
    __bf16* __restrict__ qhh, __bf16* __restrict__ qhl,
    __bf16* __restrict__ khh, __bf16* __restrict__ khl,
    __bf16* __restrict__ vhT, float uscale) {
  __shared__ __bf16 As[2][128][40];
  __shared__ __bf16 Bs[2][128][40];
  int tid = threadIdx.x;
  int wid = tid >> 6, lane = tid & 63;
  int lrow = lane & 15, quad = lane >> 4;
  int m0 = blockIdx.x * 128, n0 = blockIdx.y * 128;
  int z = blockIdx.z;
  int t = z >> 4, b = z & 15;
  const float* Ab = QF3 + (long long)z * 1052672;
  const __bf16* Bbh = Wth + (long long)t * 524288;
  const __bf16* Bbl = Wtl + (long long)t * 524288;

  int wm0 = (wid & 1) * 64, wn0 = (wid >> 1) * 64;
  // A staging: transpose fp32 [k][f] -> LDS [f][k] with on-the-fly split
  int floc = tid & 127;
  int kg = (tid >> 7) * 4;                 // 0 or 4
  const float* Acol = Ab + min(m0 + floc, 1024);
  // B staging: plain copy of pre-split planes
  int srow = tid >> 1, shalf = tid & 1;

  f32x4 acc[4][4];
#pragma unroll
  for (int i = 0; i < 4; i++)
#pragma unroll
    for (int j = 0; j < 4; j++) acc[i][j] = (f32x4){0.f, 0.f, 0.f, 0.f};

  for (int k0 = 0; k0 < 1024; k0 += 32) {
#pragma unroll
    for (int it = 0; it < 4; it++) {
      int kko = kg + it * 8;               // 0,8,16,24 (+4)
      float v0 = Acol[(long long)(k0 + kko + 0) * 1028];
      float v1 = Acol[(long long)(k0 + kko + 1) * 1028];
      float v2 = Acol[(long long)(k0 + kko + 2) * 1028];
      float v3 = Acol[(long long)(k0 + kko + 3) * 1028];
      __bf16 h0 = (__bf16)v0, h1 = (__bf16)v1, h2 = (__bf16)v2, h3 = (__bf16)v3;
      unsigned short u0, u1, u2, u3;
      __builtin_memcpy(&u0, &h0, 2); __builtin_memcpy(&u1, &h1, 2);
      __builtin_memcpy(&u2, &h2, 2); __builtin_memcpy(&u3, &h3, 2);
      uint2 hu = make_uint2((unsigned)u0 | ((unsigned)u1 << 16),
                            (unsigned)u2 | ((unsigned)u3 << 16));
      __bf16 l0 = (__bf16)(v0 - (float)h0), l1 = (__bf16)(v1 - (float)h1);
      __bf16 l2 = (__bf16)(v2 - (float)h2), l3 = (__bf16)(v3 - (float)h3);
      __builtin_memcpy(&u0, &l0, 2); __builtin_memcpy(&u1, &l1, 2);
      __builtin_memcpy(&u2, &l2, 2); __builtin_memcpy(&u3, &l3, 2);
      uint2 lu = make_uint2((unsigned)u0 | ((unsigned)u1 << 16),
                            (unsigned)u2 | ((unsigned)u3 << 16));
      *(uint2*)&As[0][floc][kko] = hu;
      *(uint2*)&As[1][floc][kko] = lu;
    }
    {
      const __bf16* s = Bbh + (long long)(n0 + srow) * 1024 + k0 + shalf * 16;
      uint4* d = (uint4*)&Bs[0][srow][shalf * 16];
      d[0] = ((const uint4*)s)[0]; d[1] = ((const uint4*)s)[1];
      s = Bbl + (long long)(n0 + srow) * 1024 + k0 + shalf * 16;
      d = (uint4*)&Bs[1][srow][shalf * 16];
      d[0] = ((const uint4*)s)[0]; d[1] = ((const uint4*)s)[1];
    }
    __syncthreads();

    bf16x8 bh[4], bl[4];
#pragma unroll
    for (int nt = 0; nt < 4; nt++) {
      int r = wn0 + nt * 16 + lrow;
      bh[nt] = ldfrag(&Bs[0][r][quad * 8]);
      bl[nt] = ldfrag(&Bs[1][r][quad * 8]);
    }
#pragma unroll
    for (int mt = 0; mt < 4; mt++) {
      int r = wm0 + mt * 16 + lrow;
      bf16x8 ah = ldfrag(&As[0][r][quad * 8]);
      bf16x8 al = ldfrag(&As[1][r][quad * 8]);
#pragma unroll
      for (int nt = 0; nt < 4; nt++) {
        acc[mt][nt] = __builtin_amdgcn_mfma_f32_16x16x32_bf16(ah, bh[nt], acc[mt][nt], 0, 0, 0);
        acc[mt][nt] = __builtin_amdgcn_mfma_f32_16x16x32_bf16(ah, bl[nt], acc[mt][nt], 0, 0, 0);
        acc[mt][nt] = __builtin_amdgcn_mfma_f32_16x16x32_bf16(al, bh[nt], acc[mt][nt], 0, 0, 0);
      }
    }
    __syncthreads();
  }

  // epilogue
  __bf16* Ch = (t == 0) ? qhh : khh;
  __bf16* Cl = (t == 0) ? qhl : khl;
#pragma unroll
  for (int mt = 0; mt < 4; mt++) {
#pragma unroll
    for (int nt = 0; nt < 4; nt++) {
      int gn = n0 + wn0 + nt * 16 + lrow;
      float bn = bias3[t * 512 + gn];
      float vn = wf3[t * 512 + gn];
      int gmb = m0 + wm0 + mt * 16 + quad * 4;
      if (t < 2) {
#pragma unroll
        for (int r = 0; r < 4; r++) {
          int gm = gmb + r;
          if (gm < FL) {
            float val = acc[mt][nt][r] + bn + uscale * (float)gm * vn;
            long long o = ((long long)b * FL + gm) * 512 + gn;
            __bf16 h = (__bf16)val;
            Ch[o] = h;
            Cl[o] = (__bf16)(val - (float)h);
          }
        }
      } else {
        int hh = gn >> 6, dd = gn & 63;
        long long ob = ((long long)(b * 8 + hh) * 64 + dd) * 1152;
#pragma unroll
        for (int r = 0; r < 4; r++) {
          int gm = gmb + r;
          if (gm < FL) {
            float val = acc[mt][nt][r] + bn + uscale * (float)gm * vn;
            vhT[ob + gm] = (__bf16)val;
          }
        }
      }
    }
  }
}

// ---------------------------------------------------------------------------
// Out projection GEMM (1-term): A = ctx bf16 [b][f][512], B = Woh [o][512].
// Writes ybT[b][o=1024][f=1025] fp32 (transposed for coalesced irfft reads).
__global__ __launch_bounds__(256) void oproj_gemm(
    const __bf16* __restrict__ ctx, const __bf16* __restrict__ Woh,
    const float* __restrict__ bo, float* __restrict__ ybT) {
  __shared__ __bf16 As[128][40];
  __shared__ __bf16 Bs[128][40];
  int tid = threadIdx.x;
  int wid = tid >> 6, lane = tid & 63;
  int lrow = lane & 15, quad = lane >> 4;
  int m0 = blockIdx.x * 128, n0 = blockIdx.y * 128;
  int z = blockIdx.z;   // b
  const __bf16* Ab = ctx + (long long)z * 524800;
  int wm0 = (wid & 1) * 64, wn0 = (wid >> 1) * 64;
  int srow = tid >> 1, shalf = tid & 1;
  int arow = min(m0 + srow, FL - 1);

  f32x4 acc[4][4];
#pragma unroll
  for (int i = 0; i < 4; i++)
#pragma unroll
    for (int j = 0; j < 4; j++) acc[i][j] = (f32x4){0.f, 0.f, 0.f, 0.f};

  for (int k0 = 0; k0 < 512; k0 += 32) {
    {
      const __bf16* s = Ab + (long long)arow * 512 + k0 + shalf * 16;
      uint4* d = (uint4*)&As[srow][shalf * 16];
      d[0] = ((const uint4*)s)[0]; d[1] = ((const uint4*)s)[1];
      s = Woh + (long long)(n0 + srow) * 512 + k0 + shalf * 16;
      d = (uint4*)&Bs[srow][shalf * 16];
      d[0] = ((const uint4*)s)[0]; d[1] = ((const uint4*)s)[1];
    }
    __syncthreads();
    bf16x8 bh[4];
#pragma unroll
    for (int nt = 0; nt < 4; nt++) bh[nt] = ldfrag(&Bs[wn0 + nt * 16 + lrow][quad * 8]);
#pragma unroll
    for (int mt = 0; mt < 4; mt++) {
      bf16x8 ah = ldfrag(&As[wm0 + mt * 16 + lrow][quad * 8]);
#pragma unroll
      for (int nt = 0; nt < 4; nt++)
        acc[mt][nt] = __builtin_amdgcn_mfma_f32_16x16x32_bf16(ah, bh[nt], acc[mt][nt], 0, 0, 0);
    }
    __syncthreads();
  }

#pragma unroll
  for (int mt = 0; mt < 4; mt++) {
#pragma unroll
    for (int nt = 0; nt < 4; nt++) {
      int gn = n0 + wn0 + nt * 16 + lrow;
      float bn = bo[gn];
      int gmb = m0 + wm0 + mt * 16 + quad * 4;
      long long ob = (long long)z * 1049600 + (long long)gn * 1025;
#pragma unroll
      for (int r = 0; r < 4; r++) {
        int gm = gmb + r;
        if (gm < FL) ybT[ob + gm] = acc[mt][nt][r] + bn;
      }
    }
  }
}

// ---------------------------------------------------------------------------
// Fused flash attention (verified round 3): per (b,h), 128-row Q tile,
// two-pass exact online softmax; writes normalized attn (fp32) + ctx (bf16).
static __device__ __forceinline__ void compute_S_tile(
    const __bf16 (*Kh)[72], const __bf16 (*Kl)[72],
    const bf16x8 (&qf)[2][2], int lrow, int quad, int n0, f32x4* sa) {
#pragma unroll
  for (int nt = 0; nt < 8; nt++) sa[nt] = (f32x4){0.f, 0.f, 0.f, 0.f};
#pragma unroll
  for (int kit = 0; kit < 2; kit++) {
#pragma unroll
    for (int nt = 0; nt < 8; nt++) {
      bf16x8 kh = ldfrag(&Kh[nt * 16 + lrow][kit * 32 + quad * 8]);
      bf16x8 kl = ldfrag(&Kl[nt * 16 + lrow][kit * 32 + quad * 8]);
      sa[nt] = __builtin_amdgcn_mfma_f32_16x16x32_bf16(qf[0][kit], kh, sa[nt], 0, 0, 0);
      sa[nt] = __builtin_amdgcn_mfma_f32_16x16x32_bf16(qf[0][kit], kl, sa[nt], 0, 0, 0);
      sa[nt] = __builtin_amdgcn_mfma_f32_16x16x32_bf16(qf[1][kit], kh, sa[nt], 0, 0, 0);
    }
  }
#pragma unroll
  for (int nt = 0; nt < 8; nt++) {
    int gn = n0 + nt * 16 + lrow;
    bool ok = gn < FL;
#pragma unroll
    for (int r = 0; r < 4; r++) sa[nt][r] = ok ? sa[nt][r] * 0.125f : -INFINITY;
  }
}

__global__ __launch_bounds__(512) void flash_kernel(
    const __bf16* __restrict__ qh_h, const __bf16* __restrict__ qh_l,
    const __bf16* __restrict__ kh_h, const __bf16* __restrict__ kh_l,
    const __bf16* __restrict__ vhT,
    float* __restrict__ attn, __bf16* __restrict__ ctxb) {
  __shared__ __align__(16) char smem[54272];
  __bf16 (*Kh)[72]  = (__bf16 (*)[72])smem;
  __bf16 (*Kl)[72]  = (__bf16 (*)[72])(smem + 18432);
  __bf16 (*P)[136]  = (__bf16 (*)[136])smem;          // aliases Kh/Kl
  __bf16 (*Bv)[136] = (__bf16 (*)[136])(smem + 36864);

  int tid = threadIdx.x;
  int wid = tid >> 6, lane = tid & 63;
  int lrow = lane & 15, quad = lane >> 4;
  int f0 = blockIdx.x * 128;
  int z = blockIdx.z;
  int b = z >> 3, h = z & 7;

  bf16x8 qf[2][2];
  {
    int rowq = min(f0 + wid * 16 + lrow, FL - 1);
    long long base = ((long long)b * FL + rowq) * 512 + h * 64 + quad * 8;
#pragma unroll
    for (int kit = 0; kit < 2; kit++) {
      qf[0][kit] = ldfrag(qh_h + base + kit * 32);
      qf[1][kit] = ldfrag(qh_l + base + kit * 32);
    }
  }

  int sp = tid >> 8, srw = (tid >> 1) & 127, shalf = tid & 1;
  const __bf16* ksrc0 = (sp ? kh_l : kh_h) + (long long)b * FL * 512 + h * 64 + shalf * 32;
  __bf16* kdst = (sp ? Kl[srw] : Kh[srw]) + shalf * 32;

  float m_i[4], l_i[4];
#pragma unroll
  for (int r = 0; r < 4; r++) { m_i[r] = -INFINITY; l_i[r] = 0.f; }

  f32x4 sa[8];

  // ---- pass 1: exact online (m, l) ----
  for (int nt0 = 0; nt0 < 9; nt0++) {
    __syncthreads();
    {
      int srowg = min(nt0 * 128 + srw, FL - 1);
      const __bf16* s = ksrc0 + (long long)srowg * 512;
#pragma unroll
      for (int u = 0; u < 4; u++) ((uint4*)kdst)[u] = ((const uint4*)s)[u];
    }
    __syncthreads();
    compute_S_tile(Kh, Kl, qf, lrow, quad, nt0 * 128, sa);
#pragma unroll
    for (int r = 0; r < 4; r++) {
      float mx = -INFINITY;
#pragma unroll
      for (int nt = 0; nt < 8; nt++) mx = fmaxf(mx, sa[nt][r]);
      for (int o = 1; o < 16; o <<= 1) mx = fmaxf(mx, __shfl_xor(mx, o, 64));
      float mn = fmaxf(m_i[r], mx);
      float al = fexp(m_i[r] - mn);
      float ps = 0.f;
#pragma unroll
      for (int nt = 0; nt < 8; nt++) ps += fexp(sa[nt][r] - mn);
      for (int o = 1; o < 16; o <<= 1) ps += __shfl_xor(ps, o, 64);
      l_i[r] = l_i[r] * al + ps;
      m_i[r] = mn;
    }
  }

  float rl[4];
#pragma unroll
  for (int r = 0; r < 4; r++) rl[r] = 1.0f / l_i[r];

  f32x4 oa[4];
#pragma unroll
  for (int j = 0; j < 4; j++) oa[j] = (f32x4){0.f, 0.f, 0.f, 0.f};

  int vrow = tid >> 3, voff = (tid & 7) * 16;
  const __bf16* vsrc0 = vhT + ((long long)z * 64 + vrow) * 1152 + voff;
  __bf16* vdst = &Bv[vrow][voff];

  // ---- pass 2: recompute S, emit attn, accumulate O = P*V ----
  float* attnz = attn + (long long)z * 1050625;
  for (int nt0 = 0; nt0 < 9; nt0++) {
    __syncthreads();
    {
      int srowg = min(nt0 * 128 + srw, FL - 1);
      const __bf16* s = ksrc0 + (long long)srowg * 512;
#pragma unroll
      for (int u = 0; u < 4; u++) ((uint4*)kdst)[u] = ((const uint4*)s)[u];
      const __bf16* vs = vsrc0 + nt0 * 128;
      ((uint4*)vdst)[0] = ((const uint4*)vs)[0];
      ((uint4*)vdst)[1] = ((const uint4*)vs)[1];
    }
    __syncthreads();
    compute_S_tile(Kh, Kl, qf, lrow, quad, nt0 * 128, sa);
    __syncthreads();
#pragma unroll
    for (int nt = 0; nt < 8; nt++) {
      int gn = nt0 * 128 + nt * 16 + lrow;
#pragma unroll
      for (int r = 0; r < 4; r++) {
        float p = fexp(sa[nt][r] - m_i[r]) * rl[r];
        int lm = wid * 16 + quad * 4 + r;
        int gm = f0 + lm;
        if (gm < FL && gn < FL) attnz[(long long)gm * FL + gn] = p;
        P[lm][nt * 16 + lrow] = (__bf16)p;
      }
    }
#pragma unroll
    for (int kk = 0; kk < 4; kk++) {
      bf16x8 pf = ldfrag(&P[wid * 16 + lrow][kk * 32 + quad * 8]);
#pragma unroll
      for (int nto = 0; nto < 4; nto++) {
        bf16x8 vf = ldfrag(&Bv[nto * 16 + lrow][kk * 32 + quad * 8]);
        oa[nto] = __builtin_amdgcn_mfma_f32_16x16x32_bf16(pf, vf, oa[nto], 0, 0, 0);
      }
    }
  }

#pragma unroll
  for (int nto = 0; nto < 4; nto++) {
#pragma unroll
    for (int r = 0; r < 4; r++) {
      int gm = f0 + wid * 16 + quad * 4 + r;
      if (gm < FL)
        ctxb[((long long)b * FL + gm) * 512 + h * 64 + nto * 16 + lrow] = (__bf16)oa[nto][r];
    }
  }
}

// ---------------------------------------------------------------------------
extern "C" void kernel_launch(void* const* d_in, const int* in_sizes, int n_in,
                              void* d_out, int out_size, void* d_ws, size_t ws_size,
                              hipStream_t stream) {
  (void)in_sizes; (void)n_in; (void)out_size; (void)ws_size;
  const float* q  = (const float*)d_in[0];
  const float* k  = (const float*)d_in[1];
  const float* v  = (const float*)d_in[2];
  const float* Wq = (const float*)d_in[3];
  const float* bq = (const float*)d_in[4];
  const float* Wk = (const float*)d_in[5];
  const float* bk = (const float*)d_in[6];
  const float* Wv = (const float*)d_in[7];
  const float* bv = (const float*)d_in[8];
  const float* Wo = (const float*)d_in[9];
  const float* bo = (const float*)d_in[10];

  float* outp = (float*)d_out;
  float* attn = outp + (long long)16 * 2048 * 512;

  float* ws = (float*)d_ws;
  float*  xT   = ws;                                   // 50,331,648 fl
  float*  QF3  = xT + 50331648;                        // 50,528,256 fl (48 x 1024 x 1028)
  float*  wf3  = QF3 + 50528256;                       //      1,536 fl
  float*  bias3= wf3 + 1536;                           //      1,536 fl
  __bf16* Wth  = (__bf16*)(bias3 + 1536);              //  1,572,864
  __bf16* Wtl  = Wth + 1572864;
  __bf16* Woh  = Wtl + 1572864;                        //    524,288
  __bf16* qhh  = Woh + 524288;                         //  8,396,800 each
  __bf16* qhl  = qhh + 8396800;
  __bf16* khh  = qhl + 8396800;
  __bf16* khl  = khh + 8396800;
  __bf16* vhT  = khl + 8396800;                        //  9,437,184
  __bf16* ctx  = (__bf16*)QF3;                         // alias (QF3 dead post-proj)
  float*  ybT  = xT;                                   // alias (xT dead post-rfft)

  transpose_x<<<dim3(64, 16, 48), 256, 0, stream>>>(q, k, v, xT);
  setup_pack<<<dim3(8204, 1, 1), 256, 0, stream>>>(Wq, Wk, Wv, Wo, bq, bk, bv,
                                                   Wth, Wtl, Woh, wf3, bias3);
  rfft3_kernel<<<dim3(256, 16, 3), 256, 0, stream>>>(xT, QF3);

  proj_gemm<<<dim3(9, 4, 48), 256, 0, stream>>>(
      QF3, Wth, Wtl, wf3, bias3, qhh, qhl, khh, khl, vhT, 1.0f / 2048.0f);

  flash_kernel<<<dim3(9, 1, 128), 512, 0, stream>>>(
      qhh, qhl, khh, khl, vhT, attn, ctx);

  oproj_gemm<<<dim3(9, 8, 16), 256, 0, stream>>>(ctx, Woh, bo, ybT);

  irfft3_kernel<<<dim3(256, 16), 256, 0, stream>>>(ybT, outp);
}